// Round 13
// baseline (154.195 us; speedup 1.0000x reference)
//
#include <hip/hip_runtime.h>

typedef unsigned short u16;
typedef unsigned int   u32;
typedef __attribute__((ext_vector_type(4)))  float f32x4;
typedef __attribute__((ext_vector_type(16))) float f32x16;
typedef __attribute__((ext_vector_type(8)))  __bf16 bf16x8;
typedef __attribute__((ext_vector_type(8)))  u16  u16x8;
typedef __attribute__((ext_vector_type(4)))  u16  u16x4;

#define HDIM 1024
#define SEQ  2048
#define NB   2
#define MROWS 4096   /* B*S */
#define QSCALE 0.18033688011111793f   /* 0.125 * log2(e) */
#define LOG2E  1.4426950408889634f
#define TOPK 64
#define TOPC 16

__device__ __forceinline__ u16 f2bf(float f) {
  u32 u = __float_as_uint(f);
  u32 r = u + 0x7FFFu + ((u >> 16) & 1u);
  return (u16)(r >> 16);
}

__device__ __forceinline__ u32 pkbf(float a, float b) {
  union { __bf16 h[2]; u32 w; } u;
  u.h[0] = (__bf16)a; u.h[1] = (__bf16)b;
  return u.w;
}

__device__ __forceinline__ void gload_lds16(const void* gp, void* lp) {
  __builtin_amdgcn_global_load_lds(
      (const __attribute__((address_space(1))) void*)gp,
      (__attribute__((address_space(3))) void*)lp, 16, 0, 0);
}

/* ---- fused prep: [0,4096) weight transpose, [4096,8192) hidden cvt,
   [8192,8224) topic GEMV1 partials ---- */
__global__ void prep_kernel(const float* __restrict__ w0, const float* __restrict__ w1,
                            const float* __restrict__ w2, const float* __restrict__ w3,
                            u16* __restrict__ wt_out,
                            const float* __restrict__ hidden, u16* __restrict__ hs_out,
                            const float* __restrict__ topic, const float* __restrict__ Wtp,
                            float* __restrict__ part1) {
  const int bid = blockIdx.x;
  const int tid = threadIdx.x;
  if (bid < 4096) {
    const int z = bid >> 10, ny = (bid >> 5) & 31, kx = bid & 31;
    const float* W = (z == 0) ? w0 : (z == 1) ? w1 : (z == 2) ? w2 : w3;
    u16* Wt = wt_out + (size_t)z * HDIM * HDIM;
    __shared__ float t[32][33];
    const int k0 = kx * 32, n0 = ny * 32;
    const int tx = tid & 31, ty = tid >> 5;
#pragma unroll
    for (int j = 0; j < 32; j += 8)
      t[ty + j][tx] = W[(size_t)(k0 + ty + j) * HDIM + n0 + tx];
    __syncthreads();
#pragma unroll
    for (int j = 0; j < 32; j += 8)
      Wt[(size_t)(n0 + ty + j) * HDIM + k0 + tx] = f2bf(t[tx][ty + j]);
  } else if (bid < 8192) {
    const size_t i = (size_t)(bid - 4096) * 256 + tid;
    f32x4 v = *(const f32x4*)(hidden + i * 4);
    u16x4 o;
#pragma unroll
    for (int e = 0; e < 4; ++e) o[e] = f2bf(v[e]);
    *(u16x4*)(hs_out + i * 4) = o;
  } else {
    const int b3 = bid - 8192;
    const int c = b3 & 15, b = b3 >> 4;
    const float* inb = topic + b * HDIM + c * TOPK;
    f32x4 acc = {};
#pragma unroll 8
    for (int k = 0; k < TOPK; ++k) {
      const f32x4 w4 = *(const f32x4*)(Wtp + (size_t)(c * TOPK + k) * HDIM + tid * 4);
      acc += inb[k] * w4;
    }
    *(f32x4*)(part1 + ((size_t)(b * TOPC + c)) * HDIM + tid * 4) = acc;
  }
}

/* ---- fused: reduce GEMV1 partials (64 cols this chunk) + GEMV2 partials ---- */
__global__ void topic_rp_kernel(const float* __restrict__ part1, const float* __restrict__ btp,
                                const float* __restrict__ Wta, float* __restrict__ part2) {
  const int c = blockIdx.x, b = blockIdx.y;
  const int t = threadIdx.x;
  __shared__ float inl[TOPK];
  if (t < TOPK) {
    float s = btp[c * TOPK + t];
#pragma unroll
    for (int cc = 0; cc < TOPC; ++cc)
      s += part1[((size_t)(b * TOPC + cc)) * HDIM + c * TOPK + t];
    inl[t] = s;
  }
  __syncthreads();
  f32x4 acc = {};
#pragma unroll 8
  for (int k = 0; k < TOPK; ++k) {
    const f32x4 w4 = *(const f32x4*)(Wta + (size_t)(c * TOPK + k) * HDIM + t * 4);
    acc += inl[k] * w4;
  }
  *(f32x4*)(part2 + ((size_t)(b * TOPC + c)) * HDIM + t * 4) = acc;
}

/* ---- topic reduce 2 + sigmoid ---- */
__global__ void topic_reduce_kernel(const float* __restrict__ part, const float* __restrict__ bias,
                                    float* __restrict__ out) {
  const int b = blockIdx.y;
  const int n = blockIdx.x * 256 + threadIdx.x;
  float s = bias[n];
#pragma unroll
  for (int c = 0; c < TOPC; ++c) s += part[((size_t)(b * TOPC + c)) * HDIM + n];
  out[b * HDIM + n] = 1.f / (1.f + __expf(-s));
}

/* ---- 128x128 bf16 MFMA GEMM.
   MODE 0: z=0 q (QSCALE), z=1 k (gate), z=2 v -> writes V^T directly to outv.
   MODE 1: bias + residual, fp32 out. ---- */
template <int MODE>
__global__ __launch_bounds__(256, 2)
void gemm_kernel(const u16* __restrict__ A, const u16* __restrict__ Wt,
                 const float* __restrict__ b0, const float* __restrict__ b1,
                 const float* __restrict__ b2, const float* __restrict__ gate,
                 const float* __restrict__ resid,
                 u16* __restrict__ outb, u16* __restrict__ outv, float* __restrict__ outf) {
  const int n0 = blockIdx.x * 128;
  const int m0 = blockIdx.y * 128;
  const int z = blockIdx.z;
  const u16* W = Wt + (size_t)z * (HDIM * HDIM);
  const float* bias = (MODE == 0) ? (z == 0 ? b0 : (z == 1 ? b1 : b2)) : b0;

  __shared__ __align__(16) u16 Alds[128 * 64];
  __shared__ __align__(16) u16 Blds[128 * 64];

  const int tid = threadIdx.x;
  const int lane = tid & 63;
  const int w = tid >> 6;
  const int wm = w >> 1, wn = w & 1;
  const int srow = tid >> 3, sslot = tid & 7;

  f32x4 acc[4][4] = {};

  for (int k0 = 0; k0 < HDIM; k0 += 64) {
    __syncthreads();
#pragma unroll
    for (int j = 0; j < 4; ++j) {
      const int row = j * 32 + srow;
      const int gs = (sslot ^ (row & 7)) * 8;
      gload_lds16(A + (size_t)(m0 + row) * HDIM + k0 + gs, Alds + j * 2048 + w * 512);
      gload_lds16(W + (size_t)(n0 + row) * HDIM + k0 + gs, Blds + j * 2048 + w * 512);
    }
    __syncthreads();
#pragma unroll
    for (int kk = 0; kk < 2; ++kk) {
      const int slot = ((((kk << 2) + (lane >> 4)) ^ (lane & 7)) << 3);
      bf16x8 af[4], bfr[4];
#pragma unroll
      for (int i = 0; i < 4; ++i) {
        af[i]  = *(const bf16x8*)(&Alds[(wm * 64 + i * 16 + (lane & 15)) * 64 + slot]);
        bfr[i] = *(const bf16x8*)(&Blds[(wn * 64 + i * 16 + (lane & 15)) * 64 + slot]);
      }
#pragma unroll
      for (int i = 0; i < 4; ++i)
#pragma unroll
        for (int jn = 0; jn < 4; ++jn)
          acc[i][jn] = __builtin_amdgcn_mfma_f32_16x16x32_bf16(af[i], bfr[jn], acc[i][jn], 0, 0, 0);
    }
  }

  const int rbase = (lane >> 4) << 2;
  if (MODE == 0 && z == 2) {
#pragma unroll
    for (int i = 0; i < 4; ++i) {
#pragma unroll
      for (int jn = 0; jn < 4; ++jn) {
        const int n = n0 + wn * 64 + jn * 16 + (lane & 15);
        const float bv = bias[n];
        const int m = m0 + wm * 64 + i * 16 + rbase;
        u16x4 o;
#pragma unroll
        for (int r = 0; r < 4; ++r) o[r] = f2bf(acc[i][jn][r] + bv);
        *(u16x4*)(outv + ((size_t)((m >> 11) * 16 + (n >> 6)) * 64 + (n & 63)) * SEQ + (m & 2047)) = o;
      }
    }
    return;
  }
#pragma unroll
  for (int i = 0; i < 4; ++i) {
#pragma unroll
    for (int jn = 0; jn < 4; ++jn) {
      const int n = n0 + wn * 64 + jn * 16 + (lane & 15);
      const float bv = bias[n];
#pragma unroll
      for (int r = 0; r < 4; ++r) {
        const int m = m0 + wm * 64 + i * 16 + rbase + r;
        float v = acc[i][jn][r] + bv;
        if (MODE == 0) {
          if (z == 0) v *= QSCALE;
          if (z == 1) v *= gate[(m >> 11) * HDIM + n];
          outb[(size_t)z * MROWS * HDIM + (size_t)m * HDIM + n] = f2bf(v);
        } else {
          v += resid[(size_t)m * HDIM + n];
          outf[(size_t)m * HDIM + n] = v;
        }
      }
    }
  }
}

/* ---- flash attention (R12 + T5 setprio around MFMA clusters — single-variable A/B):
   4 waves / 128 q-rows, 64-kv tiles, T15 pipeline QK(t+1)||PV(t). ---- */
__global__ __launch_bounds__(256, 2)
void attn_kernel(const u16* __restrict__ Q, const u16* __restrict__ K,
                 const u16* __restrict__ Vt, const float* __restrict__ mask,
                 u16* __restrict__ O) {
  const int q0 = blockIdx.x * 128;
  const int h = blockIdx.y;
  const int b = blockIdx.z;
  const size_t base = ((size_t)b * SEQ) * HDIM + h * 64;
  const size_t vtbase = (size_t)((b * 16 + h) * 64) * SEQ;
  const int tid = threadIdx.x, lane = tid & 63, w = tid >> 6;
  const int hh = lane >> 5;
  const int ql = lane & 31;
  const int NT = SEQ / 64;   /* 32 */

  __shared__ __align__(16) u16 Kss[2][64 * 64];
  __shared__ __align__(16) u16 Vts[2][64 * 64];

  bf16x8 Qf[4];
  {
    const u16* qp = Q + base + (size_t)(q0 + w * 32 + ql) * HDIM;
#pragma unroll
    for (int ds = 0; ds < 4; ++ds)
      Qf[ds] = *(const bf16x8*)(qp + ds * 16 + hh * 8);
  }

  /* staging sources (pre-swizzled global) */
  const int l3 = lane >> 3, l7 = lane & 7;
  const u16* ksrc0 = K + base + (size_t)(w * 8 + l3) * HDIM + ((l7 ^ l3) << 3);
  const u16* ksrc1 = K + base + (size_t)((4 + w) * 8 + l3) * HDIM + ((l7 ^ l3) << 3);
  const u16* vsrc0 = Vt + vtbase + (size_t)(w * 16 + l3) * SEQ + (((l7 ^ l3 ^ (w * 2)) & 7) << 3);
  const u16* vsrc1 = Vt + vtbase + (size_t)(w * 16 + 8 + l3) * SEQ + (((l7 ^ l3 ^ (w * 2 + 1)) & 7) << 3);

  /* LDS read bases */
  const u16* kaddr[4];
#pragma unroll
  for (int ds = 0; ds < 4; ++ds)
    kaddr[ds] = &Kss[0][ql * 64 + (((ds * 2 + hh) ^ (ql & 7)) << 3)];
  const u16* vaddr[2][4];
#pragma unroll
  for (int dt = 0; dt < 2; ++dt) {
    const int d = dt * 32 + ql;
    const int sw = (d & 7) ^ ((d >> 3) & 7);
#pragma unroll
    for (int c = 0; c < 4; ++c)
      vaddr[dt][c] = &Vts[0][d * 64 + (((c * 2 + hh) ^ sw) << 3)];
  }

  const float* mrow_base = mask + (size_t)b * SEQ + hh * 4;

  float m_run = -1e30f, l_run = 0.f;
  f32x16 accA = {}, accB = {};
  bf16x8 pfA[4], pfB[4];

  auto STAGEK = [&](const int buf, const int t1) {
    const size_t ko = (size_t)(t1 * 64) * HDIM;
    gload_lds16(ksrc0 + ko, &Kss[buf][w * 512]);
    gload_lds16(ksrc1 + ko, &Kss[buf][(4 + w) * 512]);
  };
  auto STAGEV = [&](const int buf, const int t1) {
    const int vo = t1 * 64;
    gload_lds16(vsrc0 + vo, &Vts[buf][w * 1024]);
    gload_lds16(vsrc1 + vo, &Vts[buf][w * 1024 + 512]);
  };

  auto EXPPACK = [&](const f32x16& s0_, const f32x16& s1_, bf16x8 (&pfout)[4]) {
    f32x16 p0_, p1_;
#pragma unroll
    for (int j = 0; j < 16; ++j) {
      p0_[j] = __builtin_amdgcn_exp2f(s0_[j] - m_run);
      p1_[j] = __builtin_amdgcn_exp2f(s1_[j] - m_run);
    }
    float r8[8];
#pragma unroll
    for (int j = 0; j < 8; ++j)
      r8[j] = (p0_[j] + p0_[j + 8]) + (p1_[j] + p1_[j + 8]);
    float rs = ((r8[0] + r8[1]) + (r8[2] + r8[3])) + ((r8[4] + r8[5]) + (r8[6] + r8[7]));
    rs += __shfl_xor(rs, 32);
    l_run += rs;
#pragma unroll
    for (int kvb = 0; kvb < 2; ++kvb) {
      const f32x16& pp = kvb ? p1_ : p0_;
#pragma unroll
      for (int s2 = 0; s2 < 2; ++s2) {
        const u32 a0 = pkbf(pp[s2 * 8 + 0], pp[s2 * 8 + 1]);
        const u32 a1 = pkbf(pp[s2 * 8 + 2], pp[s2 * 8 + 3]);
        const u32 b0v = pkbf(pp[s2 * 8 + 4], pp[s2 * 8 + 5]);
        const u32 b1v = pkbf(pp[s2 * 8 + 6], pp[s2 * 8 + 7]);
        const u32 sd0 = hh ? a0 : b0v, sd1 = hh ? a1 : b1v;
        const u32 r0 = (u32)__shfl_xor((int)sd0, 32);
        const u32 r1 = (u32)__shfl_xor((int)sd1, 32);
        union { u32 u[4]; bf16x8 v; } pu;
        pu.u[0] = hh ? r0 : a0;  pu.u[1] = hh ? r1 : a1;
        pu.u[2] = hh ? b0v : r0; pu.u[3] = hh ? b1v : r1;
        pfout[kvb * 2 + s2] = pu.v;
      }
    }
  };

  auto RESCALE = [&](const float mx) {
    const float mnew = fmaxf(m_run, mx);
    const float corr = __builtin_amdgcn_exp2f(m_run - mnew);
    m_run = mnew; l_run *= corr;
#pragma unroll
    for (int j = 0; j < 16; ++j) {
      const float cj = __shfl(corr, (j & 3) + 8 * (j >> 2) + 4 * hh);
      accA[j] *= cj; accB[j] *= cj;
    }
  };

  auto QKMM = [&](const int tq, const int kb, f32x16& s0_, f32x16& s1_, float& mx) {
    f32x16 sv0 = {}, sv1 = {};
    __builtin_amdgcn_s_setprio(1);
#pragma unroll
    for (int ds = 0; ds < 4; ++ds) {
      const bf16x8 kf0 = *(const bf16x8*)(kaddr[ds] + kb * 4096);
      const bf16x8 kf1 = *(const bf16x8*)(kaddr[ds] + kb * 4096 + 2048);
      sv0 = __builtin_amdgcn_mfma_f32_32x32x16_bf16(kf0, Qf[ds], sv0, 0, 0, 0);
      sv1 = __builtin_amdgcn_mfma_f32_32x32x16_bf16(kf1, Qf[ds], sv1, 0, 0, 0);
    }
    __builtin_amdgcn_s_setprio(0);
    f32x4 m40[4], m41[4];
    const float* mrow = mrow_base + tq * 64;
#pragma unroll
    for (int g = 0; g < 4; ++g) {
      m40[g] = *(const f32x4*)(mrow + g * 8);
      m41[g] = *(const f32x4*)(mrow + 32 + g * 8);
    }
#pragma unroll
    for (int j = 0; j < 16; ++j) {
      s0_[j] = fmaf(m40[j >> 2][j & 3], LOG2E, sv0[j]);
      s1_[j] = fmaf(m41[j >> 2][j & 3], LOG2E, sv1[j]);
    }
    float t8[8];
#pragma unroll
    for (int j = 0; j < 8; ++j)
      t8[j] = fmaxf(fmaxf(s0_[j], s0_[j + 8]), fmaxf(s1_[j], s1_[j + 8]));
    mx = fmaxf(fmaxf(fmaxf(t8[0], t8[1]), fmaxf(t8[2], t8[3])),
               fmaxf(fmaxf(t8[4], t8[5]), fmaxf(t8[6], t8[7])));
    mx = fmaxf(mx, __shfl_xor(mx, 32));
  };

  /* ---- prologue ---- */
  STAGEK(0, 0); STAGEV(0, 0);
  __syncthreads();
  STAGEK(1, 1); STAGEV(1, 1);
  {
    f32x16 s0_, s1_; float mx;
    QKMM(0, 0, s0_, s1_, mx);
    if (!__all(mx <= m_run + 8.f)) RESCALE(mx);
    EXPPACK(s0_, s1_, pfA);
  }
  __syncthreads();

  /* ---- steady: iter t computes QK(t+1) || PV(t) ---- */
  auto STEP = [&](const int t, const int X, const bf16x8 (&pfin)[4], bf16x8 (&pfout)[4]) {
    if (t + 2 < NT) STAGEK(X, t + 2);
    f32x16 s0_, s1_; float mx;
    QKMM(t + 1, X ^ 1, s0_, s1_, mx);
    const bool resc = !__all(mx <= m_run + 8.f);
    __builtin_amdgcn_s_setprio(1);
#pragma unroll
    for (int c = 0; c < 4; ++c) {
      const bf16x8 vf0 = *(const bf16x8*)(vaddr[0][c] + X * 4096);
      const bf16x8 vf1 = *(const bf16x8*)(vaddr[1][c] + X * 4096);
      accA = __builtin_amdgcn_mfma_f32_32x32x16_bf16(pfin[c], vf0, accA, 0, 0, 0);
      accB = __builtin_amdgcn_mfma_f32_32x32x16_bf16(pfin[c], vf1, accB, 0, 0, 0);
    }
    __builtin_amdgcn_s_setprio(0);
    if (resc) RESCALE(mx);
    EXPPACK(s0_, s1_, pfout);
    __syncthreads();
    if (t + 2 < NT) STAGEV(X, t + 2);
  };

  for (int t = 0; t < NT - 2; t += 2) {
    STEP(t, 0, pfA, pfB);
    STEP(t + 1, 1, pfB, pfA);
  }
  STEP(NT - 2, 0, pfA, pfB);

  /* epilogue: PV(31) from Vts[1] with pfB */
#pragma unroll
  for (int c = 0; c < 4; ++c) {
    const bf16x8 vf0 = *(const bf16x8*)(vaddr[0][c] + 4096);
    const bf16x8 vf1 = *(const bf16x8*)(vaddr[1][c] + 4096);
    accA = __builtin_amdgcn_mfma_f32_32x32x16_bf16(pfB[c], vf0, accA, 0, 0, 0);
    accB = __builtin_amdgcn_mfma_f32_32x32x16_bf16(pfB[c], vf1, accB, 0, 0, 0);
  }

  const float linv = 1.f / l_run;
#pragma unroll
  for (int j = 0; j < 16; ++j) {
    const int rq = (j & 3) + 8 * (j >> 2) + 4 * hh;
    const float lj = __shfl(linv, rq);
    const size_t orow = base + (size_t)(q0 + w * 32 + rq) * HDIM;
    O[orow + ql]      = f2bf(accA[j] * lj);
    O[orow + 32 + ql] = f2bf(accB[j] * lj);
  }
}

/* ---- row LayerNorm over 1024, fp32 ---- */
__global__ void ln_kernel(const float* __restrict__ x, const float* __restrict__ g,
                          const float* __restrict__ bb, float* __restrict__ out) {
  const int row = blockIdx.x;
  const int tid = threadIdx.x;
  const f32x4 v = *(const f32x4*)(x + (size_t)row * HDIM + tid * 4);
  float s = v[0] + v[1] + v[2] + v[3];
  float s2 = v[0] * v[0] + v[1] * v[1] + v[2] * v[2] + v[3] * v[3];
#pragma unroll
  for (int o = 1; o < 64; o <<= 1) { s += __shfl_xor(s, o); s2 += __shfl_xor(s2, o); }
  __shared__ float rs[4], rs2[4];
  if ((tid & 63) == 0) { rs[tid >> 6] = s; rs2[tid >> 6] = s2; }
  __syncthreads();
  s = rs[0] + rs[1] + rs[2] + rs[3];
  s2 = rs2[0] + rs2[1] + rs2[2] + rs2[3];
  const float mu = s * (1.f / HDIM);
  const float var = s2 * (1.f / HDIM) - mu * mu;
  const float inv = rsqrtf(var + 1e-5f);
  f32x4 o4;
#pragma unroll
  for (int e = 0; e < 4; ++e) {
    const int c = tid * 4 + e;
    o4[e] = (v[e] - mu) * inv * g[c] + bb[c];
  }
  *(f32x4*)(out + (size_t)row * HDIM + tid * 4) = o4;
}

extern "C" void kernel_launch(void* const* d_in, const int* in_sizes, int n_in,
                              void* d_out, int out_size, void* d_ws, size_t ws_size,
                              hipStream_t stream) {
  const float* hidden = (const float*)d_in[0];
  const float* topic  = (const float*)d_in[1];
  const float* mask   = (const float*)d_in[2];
  const float* Wq  = (const float*)d_in[3];  const float* bq  = (const float*)d_in[4];
  const float* Wk  = (const float*)d_in[5];  const float* bk  = (const float*)d_in[6];
  const float* Wv  = (const float*)d_in[7];  const float* bv  = (const float*)d_in[8];
  const float* Wtp = (const float*)d_in[9];  const float* btp = (const float*)d_in[10];
  const float* Wta = (const float*)d_in[11]; const float* bta = (const float*)d_in[12];
  const float* Wd  = (const float*)d_in[13]; const float* bd  = (const float*)d_in[14];
  const float* lng = (const float*)d_in[15]; const float* lnb = (const float*)d_in[16];
  float* out = (float*)d_out;

  char* ws = (char*)d_ws;
  u16* hs_bf  = (u16*)(ws);                                  /* 8 MB  */
  u16* WtAll  = (u16*)(ws + (size_t)(8u << 20));             /* 8 MB  */
  u16* qkv    = (u16*)(ws + (size_t)(16u << 20));            /* 16 MB: q,k */
  u16* ctx    = (u16*)(ws + (size_t)(40u << 20));            /* 8 MB  */
  u16* VtG    = (u16*)(ws + (size_t)(48u << 20));            /* 16 MB */
  float* xbuf = (float*)(ws + (size_t)(16u << 20));          /* aliases q,k after attn */
  float* tgate = (float*)(ws + (size_t)(64u << 20));
  float* tpart1 = (float*)(ws + (size_t)(66u << 20));
  float* tpart2 = (float*)(ws + (size_t)(67u << 20));

  prep_kernel<<<8224, 256, 0, stream>>>(Wq, Wk, Wv, Wd, WtAll, hidden, hs_bf,
                                        topic, Wtp, tpart1);
  topic_rp_kernel<<<dim3(TOPC, NB), 256, 0, stream>>>(tpart1, btp, Wta, tpart2);
  topic_reduce_kernel<<<dim3(4, NB), 256, 0, stream>>>(tpart2, bta, tgate);
  gemm_kernel<0><<<dim3(8, 32, 3), 256, 0, stream>>>(hs_bf, WtAll, bq, bk, bv, tgate,
                                                     nullptr, qkv, VtG, nullptr);
  attn_kernel<<<dim3(16, 16, NB), 256, 0, stream>>>(qkv, qkv + (size_t)MROWS * HDIM,
                                                    VtG, mask, ctx);
  gemm_kernel<1><<<dim3(8, 32, 1), 256, 0, stream>>>(ctx, WtAll + 3 * (size_t)HDIM * HDIM,
                                                     bd, nullptr, nullptr, nullptr, hidden,
                                                     nullptr, nullptr, xbuf);
  ln_kernel<<<4096, 256, 0, stream>>>(xbuf, lng, lnb, out);
}

// Round 14
// 148.361 us; speedup vs baseline: 1.0393x; 1.0393x over previous
//
#include <hip/hip_runtime.h>

typedef unsigned short u16;
typedef unsigned int   u32;
typedef __attribute__((ext_vector_type(4)))  float f32x4;
typedef __attribute__((ext_vector_type(16))) float f32x16;
typedef __attribute__((ext_vector_type(8)))  __bf16 bf16x8;
typedef __attribute__((ext_vector_type(8)))  u16  u16x8;
typedef __attribute__((ext_vector_type(4)))  u16  u16x4;

#define HDIM 1024
#define SEQ  2048
#define NB   2
#define MROWS 4096   /* B*S */
#define QSCALE 0.18033688011111793f   /* 0.125 * log2(e) */
#define LOG2E  1.4426950408889634f
#define TOPK 64
#define TOPC 16

__device__ __forceinline__ u16 f2bf(float f) {
  u32 u = __float_as_uint(f);
  u32 r = u + 0x7FFFu + ((u >> 16) & 1u);
  return (u16)(r >> 16);
}

__device__ __forceinline__ u32 pkbf(float a, float b) {
  union { __bf16 h[2]; u32 w; } u;
  u.h[0] = (__bf16)a; u.h[1] = (__bf16)b;
  return u.w;
}

__device__ __forceinline__ void gload_lds16(const void* gp, void* lp) {
  __builtin_amdgcn_global_load_lds(
      (const __attribute__((address_space(1))) void*)gp,
      (__attribute__((address_space(3))) void*)lp, 16, 0, 0);
}

/* ---- fused prep: [0,4096) weight transpose, [4096,8192) hidden cvt,
   [8192,8224) topic GEMV1 partials ---- */
__global__ void prep_kernel(const float* __restrict__ w0, const float* __restrict__ w1,
                            const float* __restrict__ w2, const float* __restrict__ w3,
                            u16* __restrict__ wt_out,
                            const float* __restrict__ hidden, u16* __restrict__ hs_out,
                            const float* __restrict__ topic, const float* __restrict__ Wtp,
                            float* __restrict__ part1) {
  const int bid = blockIdx.x;
  const int tid = threadIdx.x;
  if (bid < 4096) {
    const int z = bid >> 10, ny = (bid >> 5) & 31, kx = bid & 31;
    const float* W = (z == 0) ? w0 : (z == 1) ? w1 : (z == 2) ? w2 : w3;
    u16* Wt = wt_out + (size_t)z * HDIM * HDIM;
    __shared__ float t[32][33];
    const int k0 = kx * 32, n0 = ny * 32;
    const int tx = tid & 31, ty = tid >> 5;
#pragma unroll
    for (int j = 0; j < 32; j += 8)
      t[ty + j][tx] = W[(size_t)(k0 + ty + j) * HDIM + n0 + tx];
    __syncthreads();
#pragma unroll
    for (int j = 0; j < 32; j += 8)
      Wt[(size_t)(n0 + ty + j) * HDIM + k0 + tx] = f2bf(t[tx][ty + j]);
  } else if (bid < 8192) {
    const size_t i = (size_t)(bid - 4096) * 256 + tid;
    f32x4 v = *(const f32x4*)(hidden + i * 4);
    u16x4 o;
#pragma unroll
    for (int e = 0; e < 4; ++e) o[e] = f2bf(v[e]);
    *(u16x4*)(hs_out + i * 4) = o;
  } else {
    const int b3 = bid - 8192;
    const int c = b3 & 15, b = b3 >> 4;
    const float* inb = topic + b * HDIM + c * TOPK;
    f32x4 acc = {};
#pragma unroll 8
    for (int k = 0; k < TOPK; ++k) {
      const f32x4 w4 = *(const f32x4*)(Wtp + (size_t)(c * TOPK + k) * HDIM + tid * 4);
      acc += inb[k] * w4;
    }
    *(f32x4*)(part1 + ((size_t)(b * TOPC + c)) * HDIM + tid * 4) = acc;
  }
}

/* ---- fused: reduce GEMV1 partials (64 cols this chunk) + GEMV2 partials ---- */
__global__ void topic_rp_kernel(const float* __restrict__ part1, const float* __restrict__ btp,
                                const float* __restrict__ Wta, float* __restrict__ part2) {
  const int c = blockIdx.x, b = blockIdx.y;
  const int t = threadIdx.x;
  __shared__ float inl[TOPK];
  if (t < TOPK) {
    float s = btp[c * TOPK + t];
#pragma unroll
    for (int cc = 0; cc < TOPC; ++cc)
      s += part1[((size_t)(b * TOPC + cc)) * HDIM + c * TOPK + t];
    inl[t] = s;
  }
  __syncthreads();
  f32x4 acc = {};
#pragma unroll 8
  for (int k = 0; k < TOPK; ++k) {
    const f32x4 w4 = *(const f32x4*)(Wta + (size_t)(c * TOPK + k) * HDIM + t * 4);
    acc += inl[k] * w4;
  }
  *(f32x4*)(part2 + ((size_t)(b * TOPC + c)) * HDIM + t * 4) = acc;
}

/* ---- topic reduce 2 + sigmoid ---- */
__global__ void topic_reduce_kernel(const float* __restrict__ part, const float* __restrict__ bias,
                                    float* __restrict__ out) {
  const int b = blockIdx.y;
  const int n = blockIdx.x * 256 + threadIdx.x;
  float s = bias[n];
#pragma unroll
  for (int c = 0; c < TOPC; ++c) s += part[((size_t)(b * TOPC + c)) * HDIM + n];
  out[b * HDIM + n] = 1.f / (1.f + __expf(-s));
}

/* ---- 128x128 bf16 MFMA GEMM.
   MODE 0: z=0 q (QSCALE), z=1 k (gate), z=2 v -> writes V^T directly to outv.
   MODE 1: bias + residual, fp32 out. ---- */
template <int MODE>
__global__ __launch_bounds__(256, 2)
void gemm_kernel(const u16* __restrict__ A, const u16* __restrict__ Wt,
                 const float* __restrict__ b0, const float* __restrict__ b1,
                 const float* __restrict__ b2, const float* __restrict__ gate,
                 const float* __restrict__ resid,
                 u16* __restrict__ outb, u16* __restrict__ outv, float* __restrict__ outf) {
  const int n0 = blockIdx.x * 128;
  const int m0 = blockIdx.y * 128;
  const int z = blockIdx.z;
  const u16* W = Wt + (size_t)z * (HDIM * HDIM);
  const float* bias = (MODE == 0) ? (z == 0 ? b0 : (z == 1 ? b1 : b2)) : b0;

  __shared__ __align__(16) u16 Alds[128 * 64];
  __shared__ __align__(16) u16 Blds[128 * 64];

  const int tid = threadIdx.x;
  const int lane = tid & 63;
  const int w = tid >> 6;
  const int wm = w >> 1, wn = w & 1;
  const int srow = tid >> 3, sslot = tid & 7;

  f32x4 acc[4][4] = {};

  for (int k0 = 0; k0 < HDIM; k0 += 64) {
    __syncthreads();
#pragma unroll
    for (int j = 0; j < 4; ++j) {
      const int row = j * 32 + srow;
      const int gs = (sslot ^ (row & 7)) * 8;
      gload_lds16(A + (size_t)(m0 + row) * HDIM + k0 + gs, Alds + j * 2048 + w * 512);
      gload_lds16(W + (size_t)(n0 + row) * HDIM + k0 + gs, Blds + j * 2048 + w * 512);
    }
    __syncthreads();
#pragma unroll
    for (int kk = 0; kk < 2; ++kk) {
      const int slot = ((((kk << 2) + (lane >> 4)) ^ (lane & 7)) << 3);
      bf16x8 af[4], bfr[4];
#pragma unroll
      for (int i = 0; i < 4; ++i) {
        af[i]  = *(const bf16x8*)(&Alds[(wm * 64 + i * 16 + (lane & 15)) * 64 + slot]);
        bfr[i] = *(const bf16x8*)(&Blds[(wn * 64 + i * 16 + (lane & 15)) * 64 + slot]);
      }
#pragma unroll
      for (int i = 0; i < 4; ++i)
#pragma unroll
        for (int jn = 0; jn < 4; ++jn)
          acc[i][jn] = __builtin_amdgcn_mfma_f32_16x16x32_bf16(af[i], bfr[jn], acc[i][jn], 0, 0, 0);
    }
  }

  const int rbase = (lane >> 4) << 2;
  if (MODE == 0 && z == 2) {
#pragma unroll
    for (int i = 0; i < 4; ++i) {
#pragma unroll
      for (int jn = 0; jn < 4; ++jn) {
        const int n = n0 + wn * 64 + jn * 16 + (lane & 15);
        const float bv = bias[n];
        const int m = m0 + wm * 64 + i * 16 + rbase;
        u16x4 o;
#pragma unroll
        for (int r = 0; r < 4; ++r) o[r] = f2bf(acc[i][jn][r] + bv);
        *(u16x4*)(outv + ((size_t)((m >> 11) * 16 + (n >> 6)) * 64 + (n & 63)) * SEQ + (m & 2047)) = o;
      }
    }
    return;
  }
#pragma unroll
  for (int i = 0; i < 4; ++i) {
#pragma unroll
    for (int jn = 0; jn < 4; ++jn) {
      const int n = n0 + wn * 64 + jn * 16 + (lane & 15);
      const float bv = bias[n];
#pragma unroll
      for (int r = 0; r < 4; ++r) {
        const int m = m0 + wm * 64 + i * 16 + rbase + r;
        float v = acc[i][jn][r] + bv;
        if (MODE == 0) {
          if (z == 0) v *= QSCALE;
          if (z == 1) v *= gate[(m >> 11) * HDIM + n];
          outb[(size_t)z * MROWS * HDIM + (size_t)m * HDIM + n] = f2bf(v);
        } else {
          v += resid[(size_t)m * HDIM + n];
          outf[(size_t)m * HDIM + n] = v;
        }
      }
    }
  }
}

/* ---- flash attention (R12 base, setprio reverted, + mask folded into QK^T
   via virtual k-slice: S^T = mfma(Aext,Bext,0) + sum mfma(K,Q).
   Aext[kv][0]=mask[kv]*log2e (bf16), Bext[0][q]=1. ---- */
__global__ __launch_bounds__(256, 2)
void attn_kernel(const u16* __restrict__ Q, const u16* __restrict__ K,
                 const u16* __restrict__ Vt, const float* __restrict__ mask,
                 u16* __restrict__ O) {
  const int q0 = blockIdx.x * 128;
  const int h = blockIdx.y;
  const int b = blockIdx.z;
  const size_t base = ((size_t)b * SEQ) * HDIM + h * 64;
  const size_t vtbase = (size_t)((b * 16 + h) * 64) * SEQ;
  const int tid = threadIdx.x, lane = tid & 63, w = tid >> 6;
  const int hh = lane >> 5;
  const int ql = lane & 31;
  const int NT = SEQ / 64;   /* 32 */

  __shared__ __align__(16) u16 Kss[2][64 * 64];
  __shared__ __align__(16) u16 Vts[2][64 * 64];

  bf16x8 Qf[4];
  {
    const u16* qp = Q + base + (size_t)(q0 + w * 32 + ql) * HDIM;
#pragma unroll
    for (int ds = 0; ds < 4; ++ds)
      Qf[ds] = *(const bf16x8*)(qp + ds * 16 + hh * 8);
  }

  /* staging sources (pre-swizzled global) */
  const int l3 = lane >> 3, l7 = lane & 7;
  const u16* ksrc0 = K + base + (size_t)(w * 8 + l3) * HDIM + ((l7 ^ l3) << 3);
  const u16* ksrc1 = K + base + (size_t)((4 + w) * 8 + l3) * HDIM + ((l7 ^ l3) << 3);
  const u16* vsrc0 = Vt + vtbase + (size_t)(w * 16 + l3) * SEQ + (((l7 ^ l3 ^ (w * 2)) & 7) << 3);
  const u16* vsrc1 = Vt + vtbase + (size_t)(w * 16 + 8 + l3) * SEQ + (((l7 ^ l3 ^ (w * 2 + 1)) & 7) << 3);

  /* LDS read bases */
  const u16* kaddr[4];
#pragma unroll
  for (int ds = 0; ds < 4; ++ds)
    kaddr[ds] = &Kss[0][ql * 64 + (((ds * 2 + hh) ^ (ql & 7)) << 3)];
  const u16* vaddr[2][4];
#pragma unroll
  for (int dt = 0; dt < 2; ++dt) {
    const int d = dt * 32 + ql;
    const int sw = (d & 7) ^ ((d >> 3) & 7);
#pragma unroll
    for (int c = 0; c < 4; ++c)
      vaddr[dt][c] = &Vts[0][d * 64 + (((c * 2 + hh) ^ sw) << 3)];
  }

  /* mask: one scalar per lane per 32-kv half (q-row = ql owns kv-row ql here) */
  const float* mcol_base = mask + (size_t)b * SEQ + ql;
  /* Bext: B[k=hh*8+e][q] = 1.0 at k==0 -> lanes hh==0 get bf16(1.0) in u[0] low half */
  union { u32 u[4]; bf16x8 v; } bext;
  bext.u[0] = hh ? 0u : 0x00003F80u;
  bext.u[1] = 0; bext.u[2] = 0; bext.u[3] = 0;

  float m_run = -1e30f, l_run = 0.f;
  f32x16 accA = {}, accB = {};
  bf16x8 pfA[4], pfB[4];

  auto STAGEK = [&](const int buf, const int t1) {
    const size_t ko = (size_t)(t1 * 64) * HDIM;
    gload_lds16(ksrc0 + ko, &Kss[buf][w * 512]);
    gload_lds16(ksrc1 + ko, &Kss[buf][(4 + w) * 512]);
  };
  auto STAGEV = [&](const int buf, const int t1) {
    const int vo = t1 * 64;
    gload_lds16(vsrc0 + vo, &Vts[buf][w * 1024]);
    gload_lds16(vsrc1 + vo, &Vts[buf][w * 1024 + 512]);
  };

  auto EXPPACK = [&](const f32x16& s0_, const f32x16& s1_, bf16x8 (&pfout)[4]) {
    f32x16 p0_, p1_;
#pragma unroll
    for (int j = 0; j < 16; ++j) {
      p0_[j] = __builtin_amdgcn_exp2f(s0_[j] - m_run);
      p1_[j] = __builtin_amdgcn_exp2f(s1_[j] - m_run);
    }
    float r8[8];
#pragma unroll
    for (int j = 0; j < 8; ++j)
      r8[j] = (p0_[j] + p0_[j + 8]) + (p1_[j] + p1_[j + 8]);
    float rs = ((r8[0] + r8[1]) + (r8[2] + r8[3])) + ((r8[4] + r8[5]) + (r8[6] + r8[7]));
    rs += __shfl_xor(rs, 32);
    l_run += rs;
#pragma unroll
    for (int kvb = 0; kvb < 2; ++kvb) {
      const f32x16& pp = kvb ? p1_ : p0_;
#pragma unroll
      for (int s2 = 0; s2 < 2; ++s2) {
        const u32 a0 = pkbf(pp[s2 * 8 + 0], pp[s2 * 8 + 1]);
        const u32 a1 = pkbf(pp[s2 * 8 + 2], pp[s2 * 8 + 3]);
        const u32 b0v = pkbf(pp[s2 * 8 + 4], pp[s2 * 8 + 5]);
        const u32 b1v = pkbf(pp[s2 * 8 + 6], pp[s2 * 8 + 7]);
        const u32 sd0 = hh ? a0 : b0v, sd1 = hh ? a1 : b1v;
        const u32 r0 = (u32)__shfl_xor((int)sd0, 32);
        const u32 r1 = (u32)__shfl_xor((int)sd1, 32);
        union { u32 u[4]; bf16x8 v; } pu;
        pu.u[0] = hh ? r0 : a0;  pu.u[1] = hh ? r1 : a1;
        pu.u[2] = hh ? b0v : r0; pu.u[3] = hh ? b1v : r1;
        pfout[kvb * 2 + s2] = pu.v;
      }
    }
  };

  auto RESCALE = [&](const float mx) {
    const float mnew = fmaxf(m_run, mx);
    const float corr = __builtin_amdgcn_exp2f(m_run - mnew);
    m_run = mnew; l_run *= corr;
#pragma unroll
    for (int j = 0; j < 16; ++j) {
      const float cj = __shfl(corr, (j & 3) + 8 * (j >> 2) + 4 * hh);
      accA[j] *= cj; accB[j] *= cj;
    }
  };

  /* QK^T with mask pre-seeded via extra mfma; s0_/s1_ = final scores (log2 dom) */
  auto QKMM = [&](const int tq, const int kb, f32x16& s0_, f32x16& s1_, float& mx) {
    /* Aext[kv=ql][k=0] = mask[kv]*log2e for hh==0 lanes */
    const float mv0 = mcol_base[tq * 64];
    const float mv1 = mcol_base[tq * 64 + 32];
    union { u32 u[4]; bf16x8 v; } ae0, ae1;
    ae0.u[0] = hh ? 0u : (u32)f2bf(mv0 * LOG2E);
    ae1.u[0] = hh ? 0u : (u32)f2bf(mv1 * LOG2E);
    ae0.u[1] = ae0.u[2] = ae0.u[3] = 0;
    ae1.u[1] = ae1.u[2] = ae1.u[3] = 0;
    f32x16 sv0 = {}, sv1 = {};
    sv0 = __builtin_amdgcn_mfma_f32_32x32x16_bf16(ae0.v, bext.v, sv0, 0, 0, 0);
    sv1 = __builtin_amdgcn_mfma_f32_32x32x16_bf16(ae1.v, bext.v, sv1, 0, 0, 0);
#pragma unroll
    for (int ds = 0; ds < 4; ++ds) {
      const bf16x8 kf0 = *(const bf16x8*)(kaddr[ds] + kb * 4096);
      const bf16x8 kf1 = *(const bf16x8*)(kaddr[ds] + kb * 4096 + 2048);
      sv0 = __builtin_amdgcn_mfma_f32_32x32x16_bf16(kf0, Qf[ds], sv0, 0, 0, 0);
      sv1 = __builtin_amdgcn_mfma_f32_32x32x16_bf16(kf1, Qf[ds], sv1, 0, 0, 0);
    }
    s0_ = sv0; s1_ = sv1;
    float t8[8];
#pragma unroll
    for (int j = 0; j < 8; ++j)
      t8[j] = fmaxf(fmaxf(s0_[j], s0_[j + 8]), fmaxf(s1_[j], s1_[j + 8]));
    mx = fmaxf(fmaxf(fmaxf(t8[0], t8[1]), fmaxf(t8[2], t8[3])),
               fmaxf(fmaxf(t8[4], t8[5]), fmaxf(t8[6], t8[7])));
    mx = fmaxf(mx, __shfl_xor(mx, 32));
  };

  /* ---- prologue ---- */
  STAGEK(0, 0); STAGEV(0, 0);
  __syncthreads();
  STAGEK(1, 1); STAGEV(1, 1);
  {
    f32x16 s0_, s1_; float mx;
    QKMM(0, 0, s0_, s1_, mx);
    if (!__all(mx <= m_run + 8.f)) RESCALE(mx);
    EXPPACK(s0_, s1_, pfA);
  }
  __syncthreads();

  /* ---- steady: iter t computes QK(t+1) || PV(t) ---- */
  auto STEP = [&](const int t, const int X, const bf16x8 (&pfin)[4], bf16x8 (&pfout)[4]) {
    if (t + 2 < NT) STAGEK(X, t + 2);
    f32x16 s0_, s1_; float mx;
    QKMM(t + 1, X ^ 1, s0_, s1_, mx);
    const bool resc = !__all(mx <= m_run + 8.f);
#pragma unroll
    for (int c = 0; c < 4; ++c) {
      const bf16x8 vf0 = *(const bf16x8*)(vaddr[0][c] + X * 4096);
      const bf16x8 vf1 = *(const bf16x8*)(vaddr[1][c] + X * 4096);
      accA = __builtin_amdgcn_mfma_f32_32x32x16_bf16(pfin[c], vf0, accA, 0, 0, 0);
      accB = __builtin_amdgcn_mfma_f32_32x32x16_bf16(pfin[c], vf1, accB, 0, 0, 0);
    }
    if (resc) RESCALE(mx);
    EXPPACK(s0_, s1_, pfout);
    __syncthreads();
    if (t + 2 < NT) STAGEV(X, t + 2);
  };

  for (int t = 0; t < NT - 2; t += 2) {
    STEP(t, 0, pfA, pfB);
    STEP(t + 1, 1, pfB, pfA);
  }
  STEP(NT - 2, 0, pfA, pfB);

  /* epilogue: PV(31) from Vts[1] with pfB */
#pragma unroll
  for (int c = 0; c < 4; ++c) {
    const bf16x8 vf0 = *(const bf16x8*)(vaddr[0][c] + 4096);
    const bf16x8 vf1 = *(const bf16x8*)(vaddr[1][c] + 4096);
    accA = __builtin_amdgcn_mfma_f32_32x32x16_bf16(pfB[c], vf0, accA, 0, 0, 0);
    accB = __builtin_amdgcn_mfma_f32_32x32x16_bf16(pfB[c], vf1, accB, 0, 0, 0);
  }

  const float linv = 1.f / l_run;
#pragma unroll
  for (int j = 0; j < 16; ++j) {
    const int rq = (j & 3) + 8 * (j >> 2) + 4 * hh;
    const float lj = __shfl(linv, rq);
    const size_t orow = base + (size_t)(q0 + w * 32 + rq) * HDIM;
    O[orow + ql]      = f2bf(accA[j] * lj);
    O[orow + 32 + ql] = f2bf(accB[j] * lj);
  }
}

/* ---- row LayerNorm over 1024, fp32 ---- */
__global__ void ln_kernel(const float* __restrict__ x, const float* __restrict__ g,
                          const float* __restrict__ bb, float* __restrict__ out) {
  const int row = blockIdx.x;
  const int tid = threadIdx.x;
  const f32x4 v = *(const f32x4*)(x + (size_t)row * HDIM + tid * 4);
  float s = v[0] + v[1] + v[2] + v[3];
  float s2 = v[0] * v[0] + v[1] * v[1] + v[2] * v[2] + v[3] * v[3];
#pragma unroll
  for (int o = 1; o < 64; o <<= 1) { s += __shfl_xor(s, o); s2 += __shfl_xor(s2, o); }
  __shared__ float rs[4], rs2[4];
  if ((tid & 63) == 0) { rs[tid >> 6] = s; rs2[tid >> 6] = s2; }
  __syncthreads();
  s = rs[0] + rs[1] + rs[2] + rs[3];
  s2 = rs2[0] + rs2[1] + rs2[2] + rs2[3];
  const float mu = s * (1.f / HDIM);
  const float var = s2 * (1.f / HDIM) - mu * mu;
  const float inv = rsqrtf(var + 1e-5f);
  f32x4 o4;
#pragma unroll
  for (int e = 0; e < 4; ++e) {
    const int c = tid * 4 + e;
    o4[e] = (v[e] - mu) * inv * g[c] + bb[c];
  }
  *(f32x4*)(out + (size_t)row * HDIM + tid * 4) = o4;
}

extern "C" void kernel_launch(void* const* d_in, const int* in_sizes, int n_in,
                              void* d_out, int out_size, void* d_ws, size_t ws_size,
                              hipStream_t stream) {
  const float* hidden = (const float*)d_in[0];
  const float* topic  = (const float*)d_in[1];
  const float* mask   = (const float*)d_in[2];
  const float* Wq  = (const float*)d_in[3];  const float* bq  = (const float*)d_in[4];
  const float* Wk  = (const float*)d_in[5];  const float* bk  = (const float*)d_in[6];
  const float* Wv  = (const float*)d_in[7];  const float* bv  = (const float*)d_in[8];
  const float* Wtp = (const float*)d_in[9];  const float* btp = (const float*)d_in[10];
  const float* Wta = (const float*)d_in[11]; const float* bta = (const float*)d_in[12];
  const float* Wd  = (const float*)d_in[13]; const float* bd  = (const float*)d_in[14];
  const float* lng = (const float*)d_in[15]; const float* lnb = (const float*)d_in[16];
  float* out = (float*)d_out;

  char* ws = (char*)d_ws;
  u16* hs_bf  = (u16*)(ws);                                  /* 8 MB  */
  u16* WtAll  = (u16*)(ws + (size_t)(8u << 20));             /* 8 MB  */
  u16* qkv    = (u16*)(ws + (size_t)(16u << 20));            /* 16 MB: q,k */
  u16* ctx    = (u16*)(ws + (size_t)(40u << 20));            /* 8 MB  */
  u16* VtG    = (u16*)(ws + (size_t)(48u << 20));            /* 16 MB */
  float* xbuf = (float*)(ws + (size_t)(16u << 20));          /* aliases q,k after attn */
  float* tgate = (float*)(ws + (size_t)(64u << 20));
  float* tpart1 = (float*)(ws + (size_t)(66u << 20));
  float* tpart2 = (float*)(ws + (size_t)(67u << 20));

  prep_kernel<<<8224, 256, 0, stream>>>(Wq, Wk, Wv, Wd, WtAll, hidden, hs_bf,
                                        topic, Wtp, tpart1);
  topic_rp_kernel<<<dim3(TOPC, NB), 256, 0, stream>>>(tpart1, btp, Wta, tpart2);
  topic_reduce_kernel<<<dim3(4, NB), 256, 0, stream>>>(tpart2, bta, tgate);
  gemm_kernel<0><<<dim3(8, 32, 3), 256, 0, stream>>>(hs_bf, WtAll, bq, bk, bv, tgate,
                                                     nullptr, qkv, VtG, nullptr);
  attn_kernel<<<dim3(16, 16, NB), 256, 0, stream>>>(qkv, qkv + (size_t)MROWS * HDIM,
                                                    VtG, mask, ctx);
  gemm_kernel<1><<<dim3(8, 32, 1), 256, 0, stream>>>(ctx, WtAll + 3 * (size_t)HDIM * HDIM,
                                                     bd, nullptr, nullptr, nullptr, hidden,
                                                     nullptr, nullptr, xbuf);
  ln_kernel<<<4096, 256, 0, stream>>>(xbuf, lng, lnb, out);
}

// Round 15
// 142.016 us; speedup vs baseline: 1.0858x; 1.0447x over previous
//
#include <hip/hip_runtime.h>

typedef unsigned short u16;
typedef unsigned int   u32;
typedef __attribute__((ext_vector_type(4)))  float f32x4;
typedef __attribute__((ext_vector_type(16))) float f32x16;
typedef __attribute__((ext_vector_type(8)))  __bf16 bf16x8;
typedef __attribute__((ext_vector_type(8)))  u16  u16x8;
typedef __attribute__((ext_vector_type(4)))  u16  u16x4;

#define HDIM 1024
#define SEQ  2048
#define NB   2
#define MROWS 4096   /* B*S */
#define QSCALE 0.18033688011111793f   /* 0.125 * log2(e) */
#define LOG2E  1.4426950408889634f
#define TOPK 64
#define TOPC 16

__device__ __forceinline__ u16 f2bf(float f) {
  u32 u = __float_as_uint(f);
  u32 r = u + 0x7FFFu + ((u >> 16) & 1u);
  return (u16)(r >> 16);
}

__device__ __forceinline__ u32 pkbf(float a, float b) {
  union { __bf16 h[2]; u32 w; } u;
  u.h[0] = (__bf16)a; u.h[1] = (__bf16)b;
  return u.w;
}

__device__ __forceinline__ void gload_lds16(const void* gp, void* lp) {
  __builtin_amdgcn_global_load_lds(
      (const __attribute__((address_space(1))) void*)gp,
      (__attribute__((address_space(3))) void*)lp, 16, 0, 0);
}

/* ---- fused prep: [0,4096) weight transpose, [4096,8192) hidden cvt,
   [8192,8224) topic GEMV1 partials ---- */
__global__ void prep_kernel(const float* __restrict__ w0, const float* __restrict__ w1,
                            const float* __restrict__ w2, const float* __restrict__ w3,
                            u16* __restrict__ wt_out,
                            const float* __restrict__ hidden, u16* __restrict__ hs_out,
                            const float* __restrict__ topic, const float* __restrict__ Wtp,
                            float* __restrict__ part1) {
  const int bid = blockIdx.x;
  const int tid = threadIdx.x;
  if (bid < 4096) {
    const int z = bid >> 10, ny = (bid >> 5) & 31, kx = bid & 31;
    const float* W = (z == 0) ? w0 : (z == 1) ? w1 : (z == 2) ? w2 : w3;
    u16* Wt = wt_out + (size_t)z * HDIM * HDIM;
    __shared__ float t[32][33];
    const int k0 = kx * 32, n0 = ny * 32;
    const int tx = tid & 31, ty = tid >> 5;
#pragma unroll
    for (int j = 0; j < 32; j += 8)
      t[ty + j][tx] = W[(size_t)(k0 + ty + j) * HDIM + n0 + tx];
    __syncthreads();
#pragma unroll
    for (int j = 0; j < 32; j += 8)
      Wt[(size_t)(n0 + ty + j) * HDIM + k0 + tx] = f2bf(t[tx][ty + j]);
  } else if (bid < 8192) {
    const size_t i = (size_t)(bid - 4096) * 256 + tid;
    f32x4 v = *(const f32x4*)(hidden + i * 4);
    u16x4 o;
#pragma unroll
    for (int e = 0; e < 4; ++e) o[e] = f2bf(v[e]);
    *(u16x4*)(hs_out + i * 4) = o;
  } else {
    const int b3 = bid - 8192;
    const int c = b3 & 15, b = b3 >> 4;
    const float* inb = topic + b * HDIM + c * TOPK;
    f32x4 acc = {};
#pragma unroll 8
    for (int k = 0; k < TOPK; ++k) {
      const f32x4 w4 = *(const f32x4*)(Wtp + (size_t)(c * TOPK + k) * HDIM + tid * 4);
      acc += inb[k] * w4;
    }
    *(f32x4*)(part1 + ((size_t)(b * TOPC + c)) * HDIM + tid * 4) = acc;
  }
}

/* ---- fused: reduce GEMV1 partials (64 cols this chunk) + GEMV2 partials ---- */
__global__ void topic_rp_kernel(const float* __restrict__ part1, const float* __restrict__ btp,
                                const float* __restrict__ Wta, float* __restrict__ part2) {
  const int c = blockIdx.x, b = blockIdx.y;
  const int t = threadIdx.x;
  __shared__ float inl[TOPK];
  if (t < TOPK) {
    float s = btp[c * TOPK + t];
#pragma unroll
    for (int cc = 0; cc < TOPC; ++cc)
      s += part1[((size_t)(b * TOPC + cc)) * HDIM + c * TOPK + t];
    inl[t] = s;
  }
  __syncthreads();
  f32x4 acc = {};
#pragma unroll 8
  for (int k = 0; k < TOPK; ++k) {
    const f32x4 w4 = *(const f32x4*)(Wta + (size_t)(c * TOPK + k) * HDIM + t * 4);
    acc += inl[k] * w4;
  }
  *(f32x4*)(part2 + ((size_t)(b * TOPC + c)) * HDIM + t * 4) = acc;
}

/* ---- topic reduce 2 + sigmoid ---- */
__global__ void topic_reduce_kernel(const float* __restrict__ part, const float* __restrict__ bias,
                                    float* __restrict__ out) {
  const int b = blockIdx.y;
  const int n = blockIdx.x * 256 + threadIdx.x;
  float s = bias[n];
#pragma unroll
  for (int c = 0; c < TOPC; ++c) s += part[((size_t)(b * TOPC + c)) * HDIM + n];
  out[b * HDIM + n] = 1.f / (1.f + __expf(-s));
}

/* ---- 128x128 bf16 MFMA GEMM.
   MODE 0: z=0 q (QSCALE), z=1 k (gate), z=2 v -> writes V^T directly to outv
           with kv quad-swap sigma (swap quads 1<->2 within each 16 rows) so the
           attn PV A-fragment needs no cross-half exchange.
   MODE 1: bias + residual, fp32 out. ---- */
template <int MODE>
__global__ __launch_bounds__(256, 2)
void gemm_kernel(const u16* __restrict__ A, const u16* __restrict__ Wt,
                 const float* __restrict__ b0, const float* __restrict__ b1,
                 const float* __restrict__ b2, const float* __restrict__ gate,
                 const float* __restrict__ resid,
                 u16* __restrict__ outb, u16* __restrict__ outv, float* __restrict__ outf) {
  const int n0 = blockIdx.x * 128;
  const int m0 = blockIdx.y * 128;
  const int z = blockIdx.z;
  const u16* W = Wt + (size_t)z * (HDIM * HDIM);
  const float* bias = (MODE == 0) ? (z == 0 ? b0 : (z == 1 ? b1 : b2)) : b0;

  __shared__ __align__(16) u16 Alds[128 * 64];
  __shared__ __align__(16) u16 Blds[128 * 64];

  const int tid = threadIdx.x;
  const int lane = tid & 63;
  const int w = tid >> 6;
  const int wm = w >> 1, wn = w & 1;
  const int srow = tid >> 3, sslot = tid & 7;

  f32x4 acc[4][4] = {};

  for (int k0 = 0; k0 < HDIM; k0 += 64) {
    __syncthreads();
#pragma unroll
    for (int j = 0; j < 4; ++j) {
      const int row = j * 32 + srow;
      const int gs = (sslot ^ (row & 7)) * 8;
      gload_lds16(A + (size_t)(m0 + row) * HDIM + k0 + gs, Alds + j * 2048 + w * 512);
      gload_lds16(W + (size_t)(n0 + row) * HDIM + k0 + gs, Blds + j * 2048 + w * 512);
    }
    __syncthreads();
#pragma unroll
    for (int kk = 0; kk < 2; ++kk) {
      const int slot = ((((kk << 2) + (lane >> 4)) ^ (lane & 7)) << 3);
      bf16x8 af[4], bfr[4];
#pragma unroll
      for (int i = 0; i < 4; ++i) {
        af[i]  = *(const bf16x8*)(&Alds[(wm * 64 + i * 16 + (lane & 15)) * 64 + slot]);
        bfr[i] = *(const bf16x8*)(&Blds[(wn * 64 + i * 16 + (lane & 15)) * 64 + slot]);
      }
#pragma unroll
      for (int i = 0; i < 4; ++i)
#pragma unroll
        for (int jn = 0; jn < 4; ++jn)
          acc[i][jn] = __builtin_amdgcn_mfma_f32_16x16x32_bf16(af[i], bfr[jn], acc[i][jn], 0, 0, 0);
    }
  }

  const int rbase = (lane >> 4) << 2;
  if (MODE == 0 && z == 2) {
    /* quad-swap write position: sigma swaps quads 1<->2 within each 16 s-rows */
    const int q4 = lane >> 4;
    const int q4s = (q4 == 1) ? 2 : (q4 == 2) ? 1 : q4;
#pragma unroll
    for (int i = 0; i < 4; ++i) {
#pragma unroll
      for (int jn = 0; jn < 4; ++jn) {
        const int n = n0 + wn * 64 + jn * 16 + (lane & 15);
        const float bv = bias[n];
        const int m = m0 + wm * 64 + i * 16 + q4s * 4;
        u16x4 o;
#pragma unroll
        for (int r = 0; r < 4; ++r) o[r] = f2bf(acc[i][jn][r] + bv);
        *(u16x4*)(outv + ((size_t)((m >> 11) * 16 + (n >> 6)) * 64 + (n & 63)) * SEQ + (m & 2047)) = o;
      }
    }
    return;
  }
#pragma unroll
  for (int i = 0; i < 4; ++i) {
#pragma unroll
    for (int jn = 0; jn < 4; ++jn) {
      const int n = n0 + wn * 64 + jn * 16 + (lane & 15);
      const float bv = bias[n];
#pragma unroll
      for (int r = 0; r < 4; ++r) {
        const int m = m0 + wm * 64 + i * 16 + rbase + r;
        float v = acc[i][jn][r] + bv;
        if (MODE == 0) {
          if (z == 0) v *= QSCALE;
          if (z == 1) v *= gate[(m >> 11) * HDIM + n];
          outb[(size_t)z * MROWS * HDIM + (size_t)m * HDIM + n] = f2bf(v);
        } else {
          v += resid[(size_t)m * HDIM + n];
          outf[(size_t)m * HDIM + n] = v;
        }
      }
    }
  }
}

/* ---- flash attention (R14 + sigma-permuted V^T => shuffle-free P pack).
   4 waves / 128 q-rows, 64-kv tiles, T15 pipeline QK(t+1)||PV(t),
   mask folded into QK^T via virtual k-slice. ---- */
__global__ __launch_bounds__(256, 2)
void attn_kernel(const u16* __restrict__ Q, const u16* __restrict__ K,
                 const u16* __restrict__ Vt, const float* __restrict__ mask,
                 u16* __restrict__ O) {
  const int q0 = blockIdx.x * 128;
  const int h = blockIdx.y;
  const int b = blockIdx.z;
  const size_t base = ((size_t)b * SEQ) * HDIM + h * 64;
  const size_t vtbase = (size_t)((b * 16 + h) * 64) * SEQ;
  const int tid = threadIdx.x, lane = tid & 63, w = tid >> 6;
  const int hh = lane >> 5;
  const int ql = lane & 31;
  const int NT = SEQ / 64;   /* 32 */

  __shared__ __align__(16) u16 Kss[2][64 * 64];
  __shared__ __align__(16) u16 Vts[2][64 * 64];

  bf16x8 Qf[4];
  {
    const u16* qp = Q + base + (size_t)(q0 + w * 32 + ql) * HDIM;
#pragma unroll
    for (int ds = 0; ds < 4; ++ds)
      Qf[ds] = *(const bf16x8*)(qp + ds * 16 + hh * 8);
  }

  /* staging sources (pre-swizzled global) */
  const int l3 = lane >> 3, l7 = lane & 7;
  const u16* ksrc0 = K + base + (size_t)(w * 8 + l3) * HDIM + ((l7 ^ l3) << 3);
  const u16* ksrc1 = K + base + (size_t)((4 + w) * 8 + l3) * HDIM + ((l7 ^ l3) << 3);
  const u16* vsrc0 = Vt + vtbase + (size_t)(w * 16 + l3) * SEQ + (((l7 ^ l3 ^ (w * 2)) & 7) << 3);
  const u16* vsrc1 = Vt + vtbase + (size_t)(w * 16 + 8 + l3) * SEQ + (((l7 ^ l3 ^ (w * 2 + 1)) & 7) << 3);

  /* LDS read bases */
  const u16* kaddr[4];
#pragma unroll
  for (int ds = 0; ds < 4; ++ds)
    kaddr[ds] = &Kss[0][ql * 64 + (((ds * 2 + hh) ^ (ql & 7)) << 3)];
  const u16* vaddr[2][4];
#pragma unroll
  for (int dt = 0; dt < 2; ++dt) {
    const int d = dt * 32 + ql;
    const int sw = (d & 7) ^ ((d >> 3) & 7);
#pragma unroll
    for (int c = 0; c < 4; ++c)
      vaddr[dt][c] = &Vts[0][d * 64 + (((c * 2 + hh) ^ sw) << 3)];
  }

  /* mask: one scalar per lane per 32-kv half (lane owns kv-row ql) */
  const float* mcol_base = mask + (size_t)b * SEQ + ql;
  /* Bext: B[k=hh*8+e][q] = 1.0 at k==0 */
  union { u32 u[4]; bf16x8 v; } bext;
  bext.u[0] = hh ? 0u : 0x00003F80u;
  bext.u[1] = 0; bext.u[2] = 0; bext.u[3] = 0;

  float m_run = -1e30f, l_run = 0.f;
  f32x16 accA = {}, accB = {};
  bf16x8 pfA[4], pfB[4];

  auto STAGEK = [&](const int buf, const int t1) {
    const size_t ko = (size_t)(t1 * 64) * HDIM;
    gload_lds16(ksrc0 + ko, &Kss[buf][w * 512]);
    gload_lds16(ksrc1 + ko, &Kss[buf][(4 + w) * 512]);
  };
  auto STAGEV = [&](const int buf, const int t1) {
    const int vo = t1 * 64;
    gload_lds16(vsrc0 + vo, &Vts[buf][w * 1024]);
    gload_lds16(vsrc1 + vo, &Vts[buf][w * 1024 + 512]);
  };

  /* shuffle-free pack: sigma-permuted V^T makes A-frag slot e = p_[g*8+e]
     uniformly for both halves. */
  auto EXPPACK = [&](const f32x16& s0_, const f32x16& s1_, bf16x8 (&pfout)[4]) {
    f32x16 p0_, p1_;
#pragma unroll
    for (int j = 0; j < 16; ++j) {
      p0_[j] = __builtin_amdgcn_exp2f(s0_[j] - m_run);
      p1_[j] = __builtin_amdgcn_exp2f(s1_[j] - m_run);
    }
    float r8[8];
#pragma unroll
    for (int j = 0; j < 8; ++j)
      r8[j] = (p0_[j] + p0_[j + 8]) + (p1_[j] + p1_[j + 8]);
    float rs = ((r8[0] + r8[1]) + (r8[2] + r8[3])) + ((r8[4] + r8[5]) + (r8[6] + r8[7]));
    rs += __shfl_xor(rs, 32);
    l_run += rs;
#pragma unroll
    for (int g = 0; g < 4; ++g) {
      const f32x16& pp = (g & 2) ? p1_ : p0_;
      const int o = (g & 1) * 8;
      union { u32 u[4]; bf16x8 v; } pu;
      pu.u[0] = pkbf(pp[o + 0], pp[o + 1]);
      pu.u[1] = pkbf(pp[o + 2], pp[o + 3]);
      pu.u[2] = pkbf(pp[o + 4], pp[o + 5]);
      pu.u[3] = pkbf(pp[o + 6], pp[o + 7]);
      pfout[g] = pu.v;
    }
  };

  auto RESCALE = [&](const float mx) {
    const float mnew = fmaxf(m_run, mx);
    const float corr = __builtin_amdgcn_exp2f(m_run - mnew);
    m_run = mnew; l_run *= corr;
#pragma unroll
    for (int j = 0; j < 16; ++j) {
      const float cj = __shfl(corr, (j & 3) + 8 * (j >> 2) + 4 * hh);
      accA[j] *= cj; accB[j] *= cj;
    }
  };

  /* QK^T with mask pre-seeded via extra mfma */
  auto QKMM = [&](const int tq, const int kb, f32x16& s0_, f32x16& s1_, float& mx) {
    const float mv0 = mcol_base[tq * 64];
    const float mv1 = mcol_base[tq * 64 + 32];
    union { u32 u[4]; bf16x8 v; } ae0, ae1;
    ae0.u[0] = hh ? 0u : (u32)f2bf(mv0 * LOG2E);
    ae1.u[0] = hh ? 0u : (u32)f2bf(mv1 * LOG2E);
    ae0.u[1] = ae0.u[2] = ae0.u[3] = 0;
    ae1.u[1] = ae1.u[2] = ae1.u[3] = 0;
    f32x16 sv0 = {}, sv1 = {};
    sv0 = __builtin_amdgcn_mfma_f32_32x32x16_bf16(ae0.v, bext.v, sv0, 0, 0, 0);
    sv1 = __builtin_amdgcn_mfma_f32_32x32x16_bf16(ae1.v, bext.v, sv1, 0, 0, 0);
#pragma unroll
    for (int ds = 0; ds < 4; ++ds) {
      const bf16x8 kf0 = *(const bf16x8*)(kaddr[ds] + kb * 4096);
      const bf16x8 kf1 = *(const bf16x8*)(kaddr[ds] + kb * 4096 + 2048);
      sv0 = __builtin_amdgcn_mfma_f32_32x32x16_bf16(kf0, Qf[ds], sv0, 0, 0, 0);
      sv1 = __builtin_amdgcn_mfma_f32_32x32x16_bf16(kf1, Qf[ds], sv1, 0, 0, 0);
    }
    s0_ = sv0; s1_ = sv1;
    float t8[8];
#pragma unroll
    for (int j = 0; j < 8; ++j)
      t8[j] = fmaxf(fmaxf(s0_[j], s0_[j + 8]), fmaxf(s1_[j], s1_[j + 8]));
    mx = fmaxf(fmaxf(fmaxf(t8[0], t8[1]), fmaxf(t8[2], t8[3])),
               fmaxf(fmaxf(t8[4], t8[5]), fmaxf(t8[6], t8[7])));
    mx = fmaxf(mx, __shfl_xor(mx, 32));
  };

  /* ---- prologue ---- */
  STAGEK(0, 0); STAGEV(0, 0);
  __syncthreads();
  STAGEK(1, 1); STAGEV(1, 1);
  {
    f32x16 s0_, s1_; float mx;
    QKMM(0, 0, s0_, s1_, mx);
    if (!__all(mx <= m_run + 8.f)) RESCALE(mx);
    EXPPACK(s0_, s1_, pfA);
  }
  __syncthreads();

  /* ---- steady: iter t computes QK(t+1) || PV(t) ---- */
  auto STEP = [&](const int t, const int X, const bf16x8 (&pfin)[4], bf16x8 (&pfout)[4]) {
    if (t + 2 < NT) STAGEK(X, t + 2);
    f32x16 s0_, s1_; float mx;
    QKMM(t + 1, X ^ 1, s0_, s1_, mx);
    const bool resc = !__all(mx <= m_run + 8.f);
#pragma unroll
    for (int c = 0; c < 4; ++c) {
      const bf16x8 vf0 = *(const bf16x8*)(vaddr[0][c] + X * 4096);
      const bf16x8 vf1 = *(const bf16x8*)(vaddr[1][c] + X * 4096);
      accA = __builtin_amdgcn_mfma_f32_32x32x16_bf16(pfin[c], vf0, accA, 0, 0, 0);
      accB = __builtin_amdgcn_mfma_f32_32x32x16_bf16(pfin[c], vf1, accB, 0, 0, 0);
    }
    if (resc) RESCALE(mx);
    EXPPACK(s0_, s1_, pfout);
    __syncthreads();
    if (t + 2 < NT) STAGEV(X, t + 2);
  };

  for (int t = 0; t < NT - 2; t += 2) {
    STEP(t, 0, pfA, pfB);
    STEP(t + 1, 1, pfB, pfA);
  }
  STEP(NT - 2, 0, pfA, pfB);

  /* epilogue: PV(31) from Vts[1] with pfB */
#pragma unroll
  for (int c = 0; c < 4; ++c) {
    const bf16x8 vf0 = *(const bf16x8*)(vaddr[0][c] + 4096);
    const bf16x8 vf1 = *(const bf16x8*)(vaddr[1][c] + 4096);
    accA = __builtin_amdgcn_mfma_f32_32x32x16_bf16(pfB[c], vf0, accA, 0, 0, 0);
    accB = __builtin_amdgcn_mfma_f32_32x32x16_bf16(pfB[c], vf1, accB, 0, 0, 0);
  }

  const float linv = 1.f / l_run;
#pragma unroll
  for (int j = 0; j < 16; ++j) {
    const int rq = (j & 3) + 8 * (j >> 2) + 4 * hh;
    const float lj = __shfl(linv, rq);
    const size_t orow = base + (size_t)(q0 + w * 32 + rq) * HDIM;
    O[orow + ql]      = f2bf(accA[j] * lj);
    O[orow + 32 + ql] = f2bf(accB[j] * lj);
  }
}

/* ---- row LayerNorm over 1024, fp32 ---- */
__global__ void ln_kernel(const float* __restrict__ x, const float* __restrict__ g,
                          const float* __restrict__ bb, float* __restrict__ out) {
  const int row = blockIdx.x;
  const int tid = threadIdx.x;
  const f32x4 v = *(const f32x4*)(x + (size_t)row * HDIM + tid * 4);
  float s = v[0] + v[1] + v[2] + v[3];
  float s2 = v[0] * v[0] + v[1] * v[1] + v[2] * v[2] + v[3] * v[3];
#pragma unroll
  for (int o = 1; o < 64; o <<= 1) { s += __shfl_xor(s, o); s2 += __shfl_xor(s2, o); }
  __shared__ float rs[4], rs2[4];
  if ((tid & 63) == 0) { rs[tid >> 6] = s; rs2[tid >> 6] = s2; }
  __syncthreads();
  s = rs[0] + rs[1] + rs[2] + rs[3];
  s2 = rs2[0] + rs2[1] + rs2[2] + rs2[3];
  const float mu = s * (1.f / HDIM);
  const float var = s2 * (1.f / HDIM) - mu * mu;
  const float inv = rsqrtf(var + 1e-5f);
  f32x4 o4;
#pragma unroll
  for (int e = 0; e < 4; ++e) {
    const int c = tid * 4 + e;
    o4[e] = (v[e] - mu) * inv * g[c] + bb[c];
  }
  *(f32x4*)(out + (size_t)row * HDIM + tid * 4) = o4;
}

extern "C" void kernel_launch(void* const* d_in, const int* in_sizes, int n_in,
                              void* d_out, int out_size, void* d_ws, size_t ws_size,
                              hipStream_t stream) {
  const float* hidden = (const float*)d_in[0];
  const float* topic  = (const float*)d_in[1];
  const float* mask   = (const float*)d_in[2];
  const float* Wq  = (const float*)d_in[3];  const float* bq  = (const float*)d_in[4];
  const float* Wk  = (const float*)d_in[5];  const float* bk  = (const float*)d_in[6];
  const float* Wv  = (const float*)d_in[7];  const float* bv  = (const float*)d_in[8];
  const float* Wtp = (const float*)d_in[9];  const float* btp = (const float*)d_in[10];
  const float* Wta = (const float*)d_in[11]; const float* bta = (const float*)d_in[12];
  const float* Wd  = (const float*)d_in[13]; const float* bd  = (const float*)d_in[14];
  const float* lng = (const float*)d_in[15]; const float* lnb = (const float*)d_in[16];
  float* out = (float*)d_out;

  char* ws = (char*)d_ws;
  u16* hs_bf  = (u16*)(ws);                                  /* 8 MB  */
  u16* WtAll  = (u16*)(ws + (size_t)(8u << 20));             /* 8 MB  */
  u16* qkv    = (u16*)(ws + (size_t)(16u << 20));            /* 16 MB: q,k */
  u16* ctx    = (u16*)(ws + (size_t)(40u << 20));            /* 8 MB  */
  u16* VtG    = (u16*)(ws + (size_t)(48u << 20));            /* 16 MB */
  float* xbuf = (float*)(ws + (size_t)(16u << 20));          /* aliases q,k after attn */
  float* tgate = (float*)(ws + (size_t)(64u << 20));
  float* tpart1 = (float*)(ws + (size_t)(66u << 20));
  float* tpart2 = (float*)(ws + (size_t)(67u << 20));

  prep_kernel<<<8224, 256, 0, stream>>>(Wq, Wk, Wv, Wd, WtAll, hidden, hs_bf,
                                        topic, Wtp, tpart1);
  topic_rp_kernel<<<dim3(TOPC, NB), 256, 0, stream>>>(tpart1, btp, Wta, tpart2);
  topic_reduce_kernel<<<dim3(4, NB), 256, 0, stream>>>(tpart2, bta, tgate);
  gemm_kernel<0><<<dim3(8, 32, 3), 256, 0, stream>>>(hs_bf, WtAll, bq, bk, bv, tgate,
                                                     nullptr, qkv, VtG, nullptr);
  attn_kernel<<<dim3(16, 16, NB), 256, 0, stream>>>(qkv, qkv + (size_t)MROWS * HDIM,
                                                    VtG, mask, ctx);
  gemm_kernel<1><<<dim3(8, 32, 1), 256, 0, stream>>>(ctx, WtAll + 3 * (size_t)HDIM * HDIM,
                                                     bd, nullptr, nullptr, nullptr, hidden,
                                                     nullptr, nullptr, xbuf);
  ln_kernel<<<4096, 256, 0, stream>>>(xbuf, lng, lnb, out);
}